// Round 1
// baseline (1069.133 us; speedup 1.0000x reference)
//
#include <hip/hip_runtime.h>

#define RR 64
#define TT 256
#define NN 1024

// One block per run. Thread t owns timestep t. Wavefront w processes cells
// (t, i = w - 2t). Dependencies (own prev cell, neighbor-thread prev cell)
// both come from wavefront w-1: register + shfl_up, LDS for wave boundaries.
extern "C" __global__ __launch_bounds__(256, 1)
void comnet_kernel(const float* __restrict__ runs,   // (R,T,N,2)
                   const float* __restrict__ comm0,  // (R,N)
                   const float* __restrict__ w1,     // (10,4)
                   const float* __restrict__ b1,     // (10)
                   const float* __restrict__ w2,     // (2,10)
                   const float* __restrict__ b2,     // (2)
                   float* __restrict__ out)          // (R,T,N)
{
    const int r    = blockIdx.x;
    const int t    = threadIdx.x;
    const int lane = t & 63;
    const int wv   = t >> 6;

    __shared__ float s_comm0[NN];
    __shared__ float s_slot[2][4];   // [parity][wave] boundary handoff

    // stage initial comm row (only thread t==0 reads it later)
    for (int k = t; k < NN; k += 256) s_comm0[k] = comm0[r * NN + k];

    // Load weights, pre-scale for the folded tanh:
    //   tanh(z) = 1 - 2*s,  s = rcp(1 + exp2(Kc*z)),  Kc = 2*log2(e)
    //   out_j  = (b2_j + sum_k w2_jk) + sum_k (-2 w2_jk) * s_k
    const float Kc = 2.885390081777927f;
    float Ax[10], Ay[10], Al[10], Ar[10], Bz[10], M0[10], M1[10];
    float C0 = b2[0], C1 = b2[1];
#pragma unroll
    for (int k = 0; k < 10; ++k) {
        Ax[k] = Kc * w1[k * 4 + 0];
        Ay[k] = Kc * w1[k * 4 + 1];
        Al[k] = Kc * w1[k * 4 + 2];
        Ar[k] = Kc * w1[k * 4 + 3];
        Bz[k] = Kc * b1[k];
        const float u0 = w2[k], u1 = w2[10 + k];
        C0 += u0; C1 += u1;
        M0[k] = -2.0f * u0;
        M1[k] = -2.0f * u1;
    }

    __syncthreads();

    const float2* xp = (const float2*)runs + (size_t)(r * TT + t) * NN;
    float*        op = out + (size_t)(r * TT + t) * NN;

    float  c_prev = 0.0f;
    float2 x0 = xp[0];      // element i   (prefetched)
    float2 x1 = xp[1];      // element i+1 (prefetched)

    const int wmax = 2 * (TT - 1) + NN - 1;   // 1533
    for (int w = 0; w <= wmax; ++w) {
        const unsigned i  = (unsigned)(w - 2 * t);
        const bool    act = (i < NN);

        // neighbor thread's previous-wavefront value
        float nb = __shfl_up(c_prev, 1, 64);
        const float sv = s_slot[(w + 1) & 1][wv > 0 ? wv - 1 : 0];
        if (lane == 0) nb = sv;   // wave 0 lane 0 (t==0) never uses nb

        // software prefetch, distance 2
        float2 x2 = x1;
        if (act & (i + 2u < NN)) x2 = xp[i + 2];

        if (act) {
            const float left = (i == 0u) ? 0.0f : c_prev;
            float rightv;
            if (t == 0) {
                rightv = (i == NN - 1u) ? 0.0f : s_comm0[i + 1];
            } else {
                rightv = (i == NN - 1u) ? 0.0f : nb;
            }

            float a0 = C0, a1 = C1;
#pragma unroll
            for (int k = 0; k < 10; ++k) {
                float z = fmaf(Ax[k], x0.x, Bz[k]);
                z = fmaf(Ay[k], x0.y, z);
                z = fmaf(Al[k], left, z);
                z = fmaf(Ar[k], rightv, z);
                const float e = __builtin_amdgcn_exp2f(z);
                const float s = __builtin_amdgcn_rcpf(1.0f + e);
                a0 = fmaf(M0[k], s, a0);
                a1 = fmaf(M1[k], s, a1);
            }
            op[i]  = a0;   // control output
            c_prev = a1;   // comm update -> left input of next cell
            x0 = x1;
            x1 = x2;
        }

        if (lane == 63) s_slot[w & 1][wv] = c_prev;
        __syncthreads();
    }
}

extern "C" void kernel_launch(void* const* d_in, const int* in_sizes, int n_in,
                              void* d_out, int out_size, void* d_ws, size_t ws_size,
                              hipStream_t stream) {
    const float* runs  = (const float*)d_in[0];
    const float* comm0 = (const float*)d_in[1];
    const float* w1    = (const float*)d_in[2];
    const float* b1    = (const float*)d_in[3];
    const float* w2    = (const float*)d_in[4];
    const float* b2    = (const float*)d_in[5];
    float* out = (float*)d_out;
    (void)in_sizes; (void)n_in; (void)out_size; (void)d_ws; (void)ws_size;

    comnet_kernel<<<dim3(RR), dim3(256), 0, stream>>>(runs, comm0, w1, b1, w2, b2, out);
}

// Round 2
// 999.537 us; speedup vs baseline: 1.0696x; 1.0696x over previous
//
#include <hip/hip_runtime.h>

#define RR 64
#define TT 256
#define NN 1024
#define CC 32            // superstep length == extra skew per wave boundary
#define RB 128           // LDS ring depth (must be > 2*CC, power of 2)
#define NSTEP 51         // ceil((2*(TT-1) + 3*CC + NN) / CC) : w up to 1629, 51*32=1632

// One block per run. Thread t owns timestep t. Wavefront w processes cell
// (t, i = w - skew(t)), skew(t) = 2t + (t/64)*CC. Intra-wave dependency via
// __shfl_up (lockstep); cross-wave-boundary dependency via LDS ring buffer,
// valid because the extra CC skew guarantees the needed value (wavefront
// w-1-CC) was produced before the last __syncthreads (every CC wavefronts).
extern "C" __global__ __launch_bounds__(256, 1)
void comnet_kernel(const float* __restrict__ runs,   // (R,T,N,2)
                   const float* __restrict__ comm0,  // (R,N)
                   const float* __restrict__ w1,     // (10,4)
                   const float* __restrict__ b1,     // (10)
                   const float* __restrict__ w2,     // (2,10)
                   const float* __restrict__ b2,     // (2)
                   float* __restrict__ out)          // (R,T,N)
{
    const int r    = blockIdx.x;
    const int t    = threadIdx.x;
    const int lane = t & 63;
    const int wv   = t >> 6;
    const int skew = 2 * t + wv * CC;          // even for all t
    const int rsel = (wv > 0) ? (wv - 1) : 0;

    __shared__ float s_comm0[NN];
    __shared__ float s_ring[4][RB];            // [wave][wavefront & (RB-1)]

    for (int k = t; k < NN; k += 256) s_comm0[k] = comm0[r * NN + k];

    // Folded tanh: tanh(z) = 1 - 2*s, s = rcp(1 + exp2(Kc*z)), Kc = 2*log2(e)
    const float Kc = 2.885390081777927f;
    float Ax[10], Ay[10], Al[10], Ar[10], Bz[10], M0[10], M1[10];
    float C0 = b2[0], C1 = b2[1];
#pragma unroll
    for (int k = 0; k < 10; ++k) {
        Ax[k] = Kc * w1[k * 4 + 0];
        Ay[k] = Kc * w1[k * 4 + 1];
        Al[k] = Kc * w1[k * 4 + 2];
        Ar[k] = Kc * w1[k * 4 + 3];
        Bz[k] = Kc * b1[k];
        const float u0 = w2[k], u1 = w2[10 + k];
        C0 += u0; C1 += u1;
        M0[k] = -2.0f * u0;
        M1[k] = -2.0f * u1;
    }

    __syncthreads();

    const float4* xp4 = (const float4*)(runs + (size_t)(r * TT + t) * NN * 2);
    float*        op  = out + (size_t)(r * TT + t) * NN;

    float  c_prev = 0.0f;
    float4 q0 = xp4[0];    // cells i0, i0+1
    float4 q1 = xp4[1];    // cells i0+2, i0+3

    // one MLP cell; returns nothing, updates c_prev / writes out
    auto cell = [&](int w, unsigned i, bool act, float xx, float xy) {
        float nb = __shfl_up(c_prev, 1, 64);
        const float rv = s_ring[rsel][(w - 1 - CC) & (RB - 1)];  // uniform addr
        if (lane == 0) nb = rv;
        if (act) {
            const float left = (i == 0u) ? 0.0f : c_prev;
            float right;
            if (t == 0) right = (i == NN - 1u) ? 0.0f : s_comm0[i + 1];
            else        right = (i == NN - 1u) ? 0.0f : nb;

            float a0 = C0, a1 = C1;
#pragma unroll
            for (int k = 0; k < 10; ++k) {
                float z = fmaf(Ax[k], xx, Bz[k]);
                z = fmaf(Ay[k], xy, z);
                z = fmaf(Al[k], left, z);
                z = fmaf(Ar[k], right, z);
                const float e = __builtin_amdgcn_exp2f(z);
                const float s = __builtin_amdgcn_rcpf(1.0f + e);
                a0 = fmaf(M0[k], s, a0);
                a1 = fmaf(M1[k], s, a1);
            }
            op[i]  = a0;
            c_prev = a1;
        }
        if (lane == 63) s_ring[wv][w & (RB - 1)] = c_prev;
    };

    for (int s = 0; s < NSTEP; ++s) {
        const int wbase = s * CC;
#pragma unroll 4
        for (int jj = 0; jj < CC; jj += 2) {
            const int w0 = wbase + jj;                 // even; i0 parity even
            const unsigned i0 = (unsigned)(w0 - skew);
            const bool act = (i0 < NN);                // covers both cells (i0 even <= N-2)

            float4 q2 = q1;                            // prefetch cells i0+4, i0+5
            if (act & (i0 + 4u < NN)) q2 = xp4[(i0 >> 1) + 2];

            cell(w0,     i0,      act, q0.x, q0.y);
            cell(w0 + 1, i0 + 1u, act, q0.z, q0.w);

            if (act) { q0 = q1; q1 = q2; }
        }
        __syncthreads();
    }
}

extern "C" void kernel_launch(void* const* d_in, const int* in_sizes, int n_in,
                              void* d_out, int out_size, void* d_ws, size_t ws_size,
                              hipStream_t stream) {
    const float* runs  = (const float*)d_in[0];
    const float* comm0 = (const float*)d_in[1];
    const float* w1    = (const float*)d_in[2];
    const float* b1    = (const float*)d_in[3];
    const float* w2    = (const float*)d_in[4];
    const float* b2    = (const float*)d_in[5];
    float* out = (float*)d_out;
    (void)in_sizes; (void)n_in; (void)out_size; (void)d_ws; (void)ws_size;

    comnet_kernel<<<dim3(RR), dim3(256), 0, stream>>>(runs, comm0, w1, b1, w2, b2, out);
}